// Round 14
// baseline (209.601 us; speedup 1.0000x reference)
//
#include <hip/hip_runtime.h>

typedef __bf16 bf16x8 __attribute__((ext_vector_type(8)));
typedef float f32x4 __attribute__((ext_vector_type(4)));
typedef float f32x2 __attribute__((ext_vector_type(2)));
typedef __fp16 fp16x2 __attribute__((ext_vector_type(2)));
typedef unsigned short ushort8 __attribute__((ext_vector_type(8)));
typedef unsigned int uint4v __attribute__((ext_vector_type(4)));
typedef unsigned int uint2v __attribute__((ext_vector_type(2)));

__device__ __forceinline__ unsigned short f2bf(float f){
    unsigned u = __float_as_uint(f);
    u += 0x7fffu + ((u >> 16) & 1u);          // RNE
    return (unsigned short)(u >> 16);
}
__device__ __forceinline__ unsigned cvt_pk_bf16(float lo, float hi){
    unsigned r;
    asm("v_cvt_pk_bf16_f32 %0, %1, %2" : "=v"(r) : "v"(lo), "v"(hi));
    return r;
}
__device__ __forceinline__ unsigned cvt_pk_f16(float lo, float hi){
    return __builtin_bit_cast(unsigned, __builtin_amdgcn_cvt_pkrtz(lo, hi));
}
__device__ __forceinline__ float fdot2(unsigned a, unsigned b, float c){
#if __has_builtin(__builtin_amdgcn_fdot2)
    return __builtin_amdgcn_fdot2(__builtin_bit_cast(fp16x2, a),
                                  __builtin_bit_cast(fp16x2, b), c, false);
#else
    float d;
    asm("v_dot2_f32_f16 %0, %1, %2, %3" : "=v"(d) : "v"(a), "v"(b), "v"(c));
    return d;
#endif
}
__device__ __forceinline__ float bflo(unsigned w){ return __uint_as_float(w << 16); }
__device__ __forceinline__ float bfhi(unsigned w){ return __uint_as_float(w & 0xffff0000u); }

// gelu via quartic Phi(x) = 0.5 + x*H(x^2), clamped to [0,1]; NO transcendentals.
__device__ __forceinline__ float gelu_poly(float x){
    float t = x * x;
    float h = fmaf(fmaf(fmaf(fmaf(2.66044e-5f, t, -7.46798e-4f), t,
                             9.014181e-3f), t, -6.5889388e-2f), t, 0.39894228f);
    float p = fmaf(x, h, 0.5f);
    p = fminf(fmaxf(p, 0.0f), 1.0f);          // folds to v_med3_f32
    return x * p;
}

#define TM 64
#define LST 136               // shorts per LDS row: 272 B, 16B-aligned, 4-bank/row rotation
#define PLANE (TM * LST)      // 8704 shorts = 17408 B

// Pack Wk/Wq/Wv (fp32 [128][128], row=k_in, col=n_out) into bf16 MFMA B-fragment
// lane order: frag b=(p*4+ks)*8+nf, lane l holds W[ks*32+(l>>4)*8+j][nf*16+(l&15)].
__global__ void pack_w_kernel(const float* __restrict__ Wk, const float* __restrict__ Wq,
                              const float* __restrict__ Wv, unsigned short* __restrict__ wp){
    int b = blockIdx.x;      // 0..95
    int lane = threadIdx.x;  // 0..63
    int p  = b >> 5;
    int ks = (b >> 3) & 3;
    int nf = b & 7;
    const float* W = (p == 0) ? Wk : ((p == 1) ? Wq : Wv);
    int k0  = ks * 32 + (lane >> 4) * 8;
    int col = nf * 16 + (lane & 15);
    unsigned short* dst = wp + ((size_t)b * 64 + lane) * 8;
    #pragma unroll
    for (int j = 0; j < 8; ++j) dst[j] = f2bf(W[(size_t)(k0 + j) * 128 + col]);
}

__global__ __launch_bounds__(256, 4) void fused_tcross(
        const float* __restrict__ x, const unsigned short* __restrict__ wp,
        const float* __restrict__ bk, const float* __restrict__ bq,
        const float* __restrict__ bv, float* __restrict__ out){
    // TWO planes only (34816 B -> 4 blocks/CU):
    //   p0: x (staged; af hoisted to regs) -> q bf16 ; p1: k bf16 -> v f16
    //   after einsums: planes 0+1 together hold res fp32 [TM][LST].
    __shared__ __align__(16) unsigned short smem[2 * PLANE];

    const int tid  = threadIdx.x;
    const int lane = tid & 63;
    const int wave = tid >> 6;
    const int c16  = lane & 15;
    const int kg   = lane >> 4;
    const long long row0 = (long long)blockIdx.x * TM;

    // bias prefetch at col (wave*2+j)*16 + c16 (proj order: k, q, v)
    float bpk[2], bpq[2], bpv[2];
    #pragma unroll
    for (int j = 0; j < 2; ++j){
        int col = (wave * 2 + j) * 16 + c16;
        bpk[j] = bk[col];
        bpq[j] = bq[col];
        bpv[j] = bv[col];
    }

    // ---- stage x: fp32 -> bf16 LDS p0; residual kept as the SAME packed bf16 words ----
    const float* xblk = x + row0 * 128;
    unsigned rbf[16];                              // 16 VGPR instead of 32 fp32
    #pragma unroll
    for (int it = 0; it < 8; ++it){
        int e = tid * 4 + it * 1024;               // 64*128 = 8192 elems
        f32x4 v = *(const f32x4*)(xblk + e);
        uint2v w;
        w[0] = cvt_pk_bf16(v[0], v[1]);
        w[1] = cvt_pk_bf16(v[2], v[3]);
        rbf[2 * it] = w[0]; rbf[2 * it + 1] = w[1];
        *(uint2v*)&smem[(e >> 7) * LST + (e & 127)] = w;
    }
    __syncthreads();                               // B1: x visible to all

    // ---- A-fragments hoisted ONCE to registers (reused by k, q, v projections) ----
    bf16x8 af[4][4];
    #pragma unroll
    for (int m = 0; m < 4; ++m)
        #pragma unroll
        for (int ks = 0; ks < 4; ++ks)
            af[m][ks] = __builtin_bit_cast(bf16x8,
                *(const ushort8*)&smem[(m * 16 + c16) * LST + ks * 32 + kg * 8]);
    __syncthreads();                               // B2: all x reads done; p0 reusable

    // ---- k-proj -> p1 (bf16), q-proj -> p0 (bf16); wp p index: k=0, q=1 ----
    #pragma unroll 1
    for (int pi = 0; pi < 2; ++pi){
        f32x4 acc[4][2];
        const f32x4 zero = {0.f, 0.f, 0.f, 0.f};
        #pragma unroll
        for (int m = 0; m < 4; ++m){ acc[m][0] = zero; acc[m][1] = zero; }
        #pragma unroll
        for (int ks = 0; ks < 4; ++ks){
            #pragma unroll
            for (int j = 0; j < 2; ++j){
                const int nf = wave * 2 + j;
                const size_t fidx = ((size_t)((pi * 4 + ks) * 8 + nf) * 64 + lane) * 8;
                bf16x8 wfrag = __builtin_bit_cast(bf16x8, *(const ushort8*)(wp + fidx));
                #pragma unroll
                for (int m = 0; m < 4; ++m)
                    acc[m][j] = __builtin_amdgcn_mfma_f32_16x16x32_bf16(
                        af[m][ks], wfrag, acc[m][j], 0, 0, 0);
            }
        }
        unsigned short* sp = smem + (pi == 0 ? PLANE : 0);
        #pragma unroll
        for (int j = 0; j < 2; ++j){
            const int col = (wave * 2 + j) * 16 + c16;
            const float bb = (pi == 0) ? bpk[j] : bpq[j];
            #pragma unroll
            for (int m = 0; m < 4; ++m){
                float g0 = gelu_poly(acc[m][j][0] + bb);
                float g1 = gelu_poly(acc[m][j][1] + bb);
                float g2 = gelu_poly(acc[m][j][2] + bb);
                float g3 = gelu_poly(acc[m][j][3] + bb);
                unsigned u01 = cvt_pk_bf16(g0, g1);
                unsigned u23 = cvt_pk_bf16(g2, g3);
                const int r = m * 16 + kg * 4;
                sp[(r + 0) * LST + col] = (unsigned short)u01;
                sp[(r + 1) * LST + col] = (unsigned short)(u01 >> 16);
                sp[(r + 2) * LST + col] = (unsigned short)u23;
                sp[(r + 3) * LST + col] = (unsigned short)(u23 >> 16);
            }
        }
    }
    __syncthreads();                               // B3: k,q visible

    // ---- y-einsum: 4 lanes/row, lane owns g = {2*sub, 2*sub+1}; y stays in regs ----
    const int row = tid >> 2;
    const int sub = tid & 3;
    const unsigned short* krow = smem + PLANE + row * LST;   // k bf16 (p1)
    const unsigned short* qrow = smem + row * LST;           // q bf16 (p0)

    f32x2 y2[8];
    #pragma unroll
    for (int e = 0; e < 8; ++e) y2[e] = (f32x2){0.f, 0.f};
    #pragma unroll
    for (int f = 0; f < 16; ++f){
        uint4v ku = *(const uint4v*)(krow + f * 8);                 // k[f][0..7]
        unsigned qw = *(const unsigned*)(qrow + f * 8 + sub * 2);   // q[f][g0..g0+1]
        f32x2 qq = {bflo(qw), bfhi(qw)};
        float kf[8] = {bflo(ku[0]), bfhi(ku[0]), bflo(ku[1]), bfhi(ku[1]),
                       bflo(ku[2]), bfhi(ku[2]), bflo(ku[3]), bfhi(ku[3])};
        #pragma unroll
        for (int e = 0; e < 8; ++e){
            f32x2 kk = {kf[e], kf[e]};
            y2[e] += kk * qq;                 // v_pk_fma_f32
        }
    }
    unsigned yp0[4], yp1[4];
    #pragma unroll
    for (int i = 0; i < 4; ++i){
        yp0[i] = cvt_pk_f16(y2[2*i][0], y2[2*i+1][0]);
        yp1[i] = cvt_pk_f16(y2[2*i][1], y2[2*i+1][1]);
    }

    // ---- v-proj MFMAs (register-only: af regs + W from L2) — overlaps y latency ----
    f32x4 vacc[4][2];
    {
        const f32x4 zero = {0.f, 0.f, 0.f, 0.f};
        #pragma unroll
        for (int m = 0; m < 4; ++m){ vacc[m][0] = zero; vacc[m][1] = zero; }
        #pragma unroll
        for (int ks = 0; ks < 4; ++ks){
            #pragma unroll
            for (int j = 0; j < 2; ++j){
                const int nf = wave * 2 + j;
                const size_t fidx = ((size_t)((2 * 4 + ks) * 8 + nf) * 64 + lane) * 8;
                bf16x8 wfrag = __builtin_bit_cast(bf16x8, *(const ushort8*)(wp + fidx));
                #pragma unroll
                for (int m = 0; m < 4; ++m)
                    vacc[m][j] = __builtin_amdgcn_mfma_f32_16x16x32_bf16(
                        af[m][ks], wfrag, vacc[m][j], 0, 0, 0);
            }
        }
    }
    __syncthreads();                               // B4: all y-phase k/q reads done

    // ---- v epilogue -> p1 (f16, over dead k) ----
    {
        unsigned short* sp = smem + PLANE;
        #pragma unroll
        for (int j = 0; j < 2; ++j){
            const int col = (wave * 2 + j) * 16 + c16;
            const float bb = bpv[j];
            #pragma unroll
            for (int m = 0; m < 4; ++m){
                float g0 = gelu_poly(vacc[m][j][0] + bb);
                float g1 = gelu_poly(vacc[m][j][1] + bb);
                float g2 = gelu_poly(vacc[m][j][2] + bb);
                float g3 = gelu_poly(vacc[m][j][3] + bb);
                unsigned u01 = cvt_pk_f16(g0, g1);
                unsigned u23 = cvt_pk_f16(g2, g3);
                const int r = m * 16 + kg * 4;
                sp[(r + 0) * LST + col] = (unsigned short)u01;
                sp[(r + 1) * LST + col] = (unsigned short)(u01 >> 16);
                sp[(r + 2) * LST + col] = (unsigned short)u23;
                sp[(r + 3) * LST + col] = (unsigned short)(u23 >> 16);
            }
        }
    }
    __syncthreads();                               // B5: v visible

    // ---- res-einsum via v_dot2_f32_f16 ----
    const unsigned short* vrow = smem + PLANE + row * LST;   // v f16 (p1)
    f32x2 rr[16];
    #pragma unroll
    for (int f = 0; f < 16; ++f){
        uint4v vv = *(const uint4v*)(vrow + f * 8);     // v[f][e] f16 pairs over e
        float a0 = 0.f, a1 = 0.f;
        #pragma unroll
        for (int i = 0; i < 4; ++i){
            a0 = fdot2(vv[i], yp0[i], a0);
            a1 = fdot2(vv[i], yp1[i], a1);
        }
        rr[f] = (f32x2){a0, a1};                        // res[f][g0], res[f][g1]
    }
    __syncthreads();                               // B6: all v reads done

    // ---- res fp32 overlay spanning planes 0+1 ----
    float* s_res = (float*)smem;   // [TM][LST] fp32 = 34816 B = both planes
    #pragma unroll
    for (int f = 0; f < 16; ++f)
        *(f32x2*)&s_res[row * LST + f * 8 + sub * 2] = rr[f];
    __syncthreads();                               // B7

    // ---- coalesced store: out = res + x (residual from packed bf16 regs) ----
    float* outb = out + row0 * 128;
    #pragma unroll
    for (int it = 0; it < 8; ++it){
        int e = tid * 4 + it * 1024;
        f32x4 rv = *(const f32x4*)&s_res[(e >> 7) * LST + (e & 127)];
        unsigned w0 = rbf[2 * it], w1 = rbf[2 * it + 1];
        rv += (f32x4){bflo(w0), bfhi(w0), bflo(w1), bfhi(w1)};
        *(f32x4*)(outb + e) = rv;
    }
}

extern "C" void kernel_launch(void* const* d_in, const int* in_sizes, int n_in,
                              void* d_out, int out_size, void* d_ws, size_t ws_size,
                              hipStream_t stream){
    const float* x  = (const float*)d_in[0];
    const float* Wk = (const float*)d_in[1];
    const float* bk = (const float*)d_in[2];
    const float* Wq = (const float*)d_in[3];
    const float* bq = (const float*)d_in[4];
    const float* Wv = (const float*)d_in[5];
    const float* bv = (const float*)d_in[6];
    float* out = (float*)d_out;
    unsigned short* wp = (unsigned short*)d_ws;  // 96 KB of bf16 W fragments

    const int B = in_sizes[0] / 128;             // 524288, multiple of TM=64

    pack_w_kernel<<<96, 64, 0, stream>>>(Wk, Wq, Wv, wp);
    fused_tcross<<<B / TM, 256, 0, stream>>>(x, wp, bk, bq, bv, out);

    (void)n_in; (void)out_size; (void)ws_size;
}